// Round 4
// baseline (25.748 us; speedup 1.0000x reference)
//
#include <hip/hip_runtime.h>
#include <math.h>

// PositionalEncoding: out = x * sqrt(512) + pe, pe interleaved sin/cos of
// positions[b,s] * div_term[i], div_term[i] = 10000^(-i/256), d_model = 512.
//
// Memory-bound elementwise op (~134 MB traffic, floor ~21.4 us @ 6.29 TB/s).
// Each thread handles TWO float4 from the same row (columns [4j..4j+3] and
// [4j+256..4j+259]) so a 64-lane wave covers one full 512-elem row:
//   - 2 outstanding 16B loads/lane (2x MLP vs round 3)
//   - row is wave-uniform -> readfirstlane -> positions via scalar load
//   - second div_term pair is dt*0.01 exactly (10000^(-128/256) = 1/100),
//     so still only one v_exp per thread for 8 outputs.
// Non-temporal hints: pure streaming, no reuse.

#define D_MODEL 512

typedef float f32x4 __attribute__((ext_vector_type(4)));

__global__ __launch_bounds__(256) void pe_kernel(
    const f32x4* __restrict__ x,
    const int*   __restrict__ positions,
    f32x4*       __restrict__ out)
{
    const float SQRT_D   = 22.627416997969522f;       // sqrt(512)
    const float C2       = -0.05190512364928082f;     // -log2(10000)/256
    const float INV2PI   = 0.15915494309189535f;      // 1/(2*pi)
    const float DT_RATIO = 0.9646616199111993f;       // 10000^(-1/256)

    int t    = blockIdx.x * blockDim.x + threadIdx.x; // 0 .. nrows*64-1
    int row  = __builtin_amdgcn_readfirstlane(t >> 6);// wave-uniform -> SGPR
    int j    = t & 63;
    int base = (row << 7) + j;                        // f4 index of first vec

    f32x4 v0 = __builtin_nontemporal_load(&x[base]);
    f32x4 v1 = __builtin_nontemporal_load(&x[base + 64]);
    float pr = (float)positions[row] * INV2PI;        // scalar load, broadcast

    // pair indices: 2j, 2j+1 (first vec) and 2j+128, 2j+129 (second vec)
    float dt0 = __builtin_amdgcn_exp2f((float)(2 * j) * C2);  // 10000^(-2j/256)
    float dt1 = dt0 * DT_RATIO;
    float dt2 = dt0 * 0.01f;                          // * 10000^(-128/256)
    float dt3 = dt1 * 0.01f;

    // angles in revolutions, reduced to [0,1) for v_sin/v_cos
    float r0 = pr * dt0; r0 -= floorf(r0);
    float r1 = pr * dt1; r1 -= floorf(r1);
    float r2 = pr * dt2; r2 -= floorf(r2);
    float r3 = pr * dt3; r3 -= floorf(r3);

    f32x4 o0, o1;
    o0.x = v0.x * SQRT_D + __builtin_amdgcn_sinf(r0);
    o0.y = v0.y * SQRT_D + __builtin_amdgcn_cosf(r0);
    o0.z = v0.z * SQRT_D + __builtin_amdgcn_sinf(r1);
    o0.w = v0.w * SQRT_D + __builtin_amdgcn_cosf(r1);
    o1.x = v1.x * SQRT_D + __builtin_amdgcn_sinf(r2);
    o1.y = v1.y * SQRT_D + __builtin_amdgcn_cosf(r2);
    o1.z = v1.z * SQRT_D + __builtin_amdgcn_sinf(r3);
    o1.w = v1.w * SQRT_D + __builtin_amdgcn_cosf(r3);

    __builtin_nontemporal_store(o0, &out[base]);
    __builtin_nontemporal_store(o1, &out[base + 64]);
}

extern "C" void kernel_launch(void* const* d_in, const int* in_sizes, int n_in,
                              void* d_out, int out_size, void* d_ws, size_t ws_size,
                              hipStream_t stream) {
    const float* x   = (const float*)d_in[0];
    const int*   pos = (const int*)d_in[1];
    float*       out = (float*)d_out;

    int nrows = out_size / D_MODEL;        // 32768 rows
    int block = 256;
    int grid  = nrows / 4;                 // 64 threads/row -> 8192 blocks
    pe_kernel<<<grid, block, 0, stream>>>(
        (const f32x4*)x, pos, (f32x4*)out);
}